// Round 1
// baseline (5064.145 us; speedup 1.0000x reference)
//
#include <hip/hip_runtime.h>

#define NN 50000
#define TT 12
#define EE 800000
#define IN_C 32
#define HID 64
#define OUT_C 32

// ---------------- precompute folded gate matrices ----------------
// Mz = Wz @ Lz_w[:64]   (32x64),  Bz = bz @ Lz_w[:64] + Lz_b  (64)
// Mh = Wh @ Lh_w[:64]   (32x64),  Bh = bh @ Lh_w[:64] + Lh_b  (64)
__global__ __launch_bounds__(64) void prep_kernel(
    const float* __restrict__ Wz, const float* __restrict__ bz,
    const float* __restrict__ Lzw, const float* __restrict__ Lzb,
    const float* __restrict__ Wh, const float* __restrict__ bh,
    const float* __restrict__ Lhw, const float* __restrict__ Lhb,
    float* __restrict__ Mz, float* __restrict__ Bz,
    float* __restrict__ Mh, float* __restrict__ Bh) {
  const int j = threadIdx.x;           // 0..63  output col
  const int i = blockIdx.x;            // 0..32  (32 => bias row)
  const int h = blockIdx.y;            // 0 => z, 1 => h
  const float* W  = h ? Wh  : Wz;
  const float* b  = h ? bh  : bz;
  const float* L  = h ? Lhw : Lzw;
  const float* Lb = h ? Lhb : Lzb;
  float* M = h ? Mh : Mz;
  float* B = h ? Bh : Bz;
  if (i < IN_C) {
    float v = 0.f;
    for (int k = 0; k < HID; ++k) v += W[i * HID + k] * L[k * HID + j];
    M[i * HID + j] = v;
  } else {
    float v = Lb[j];
    for (int k = 0; k < HID; ++k) v += b[k] * L[k * HID + j];
    B[j] = v;
  }
}

// ---------------- per-timestep kernels ----------------
__global__ __launch_bounds__(256) void deg_init_kernel(float* __restrict__ deg) {
  int n = blockIdx.x * 256 + threadIdx.x;
  if (n < NN) deg[n] = 1.0f;  // self-loop weight
}

__global__ __launch_bounds__(256) void deg_kernel(const int* __restrict__ dst,
                                                  const float* __restrict__ w,
                                                  float* __restrict__ deg) {
  int e = blockIdx.x * 256 + threadIdx.x;
  if (e < EE) atomicAdd(&deg[dst[e]], w[e]);
}

// y[d] += dinv[s]*w*dinv[d] * x[s]   (8 threads per edge, 4 channels each)
__global__ __launch_bounds__(256) void scatter_kernel(const int* __restrict__ src,
                                                      const int* __restrict__ dst,
                                                      const float* __restrict__ w,
                                                      const float* __restrict__ deg,
                                                      const float* __restrict__ x,
                                                      float* __restrict__ y) {
  unsigned tid = blockIdx.x * 256u + threadIdx.x;
  unsigned e = tid >> 3;
  if (e >= EE) return;
  int c4 = (tid & 7u) * 4;
  int s = src[e], d = dst[e];
  float norm = rsqrtf(deg[s]) * w[e] * rsqrtf(deg[d]);
  const float4 xv = *(const float4*)(x + (size_t)s * IN_C + c4);
  float* yp = y + (size_t)d * IN_C + c4;
  atomicAdd(yp + 0, norm * xv.x);
  atomicAdd(yp + 1, norm * xv.y);
  atomicAdd(yp + 2, norm * xv.z);
  atomicAdd(yp + 3, norm * xv.w);
}

// acc[n][j] += (1 - sigmoid(za)) * tanh(ha)
//   yt[c] = y[n][c] + x[n][c]/deg[n]  (self-loop folded here)
//   za = Bz[j] + yt . Mz[:,j] ;  ha = Bh[j] + yt . Mh[:,j]
__global__ __launch_bounds__(256) void dense_kernel(const float* __restrict__ x,
                                                    const float* __restrict__ y,
                                                    const float* __restrict__ deg,
                                                    const float* __restrict__ Mz,
                                                    const float* __restrict__ Bz,
                                                    const float* __restrict__ Mh,
                                                    const float* __restrict__ Bh,
                                                    float* __restrict__ acc) {
  __shared__ float sMz[IN_C * HID], sMh[IN_C * HID], sBz[HID], sBh[HID];
  for (int i = threadIdx.x; i < IN_C * HID; i += 256) {
    sMz[i] = Mz[i];
    sMh[i] = Mh[i];
  }
  if (threadIdx.x < HID) {
    sBz[threadIdx.x] = Bz[threadIdx.x];
    sBh[threadIdx.x] = Bh[threadIdx.x];
  }
  __syncthreads();
  unsigned tid = blockIdx.x * 256u + threadIdx.x;
  unsigned n = tid >> 6;
  int j = tid & 63;
  if (n >= NN) return;
  float invd = 1.0f / deg[n];
  const float* xr = x + (size_t)n * IN_C;
  const float* yr = y + (size_t)n * IN_C;
  float za = sBz[j], ha = sBh[j];
#pragma unroll
  for (int c = 0; c < IN_C; ++c) {
    float yt = yr[c] + xr[c] * invd;
    za += yt * sMz[c * HID + j];
    ha += yt * sMh[c * HID + j];
  }
  float z = 1.0f / (1.0f + expf(-za));
  float t = tanhf(ha);
  acc[(size_t)n * HID + j] += (1.0f - z) * t;
}

// out[n][o] = (acc[n]/T) . W_out[:,o] + b_out[o]
__global__ __launch_bounds__(256) void out_kernel(const float* __restrict__ acc,
                                                  const float* __restrict__ W_out,
                                                  const float* __restrict__ b_out,
                                                  float* __restrict__ out) {
  __shared__ float sW[HID * OUT_C], sB[OUT_C];
  for (int i = threadIdx.x; i < HID * OUT_C; i += 256) sW[i] = W_out[i];
  if (threadIdx.x < OUT_C) sB[threadIdx.x] = b_out[threadIdx.x];
  __syncthreads();
  unsigned tid = blockIdx.x * 256u + threadIdx.x;
  unsigned n = tid >> 5;
  int o = tid & 31;
  if (n >= NN) return;
  const float* ar = acc + (size_t)n * HID;
  float v = 0.f;
#pragma unroll
  for (int k = 0; k < HID; ++k) v += ar[k] * sW[k * OUT_C + o];
  out[(size_t)n * OUT_C + o] = v * (1.0f / (float)TT) + sB[o];
}

extern "C" void kernel_launch(void* const* d_in, const int* in_sizes, int n_in,
                              void* d_out, int out_size, void* d_ws, size_t ws_size,
                              hipStream_t stream) {
  const float* x      = (const float*)d_in[0];   // [T,N,32]
  const int*   ei     = (const int*)d_in[1];     // [T,2,E]
  const float* ew     = (const float*)d_in[2];   // [T,E]
  const float* Wz     = (const float*)d_in[3];
  const float* bz     = (const float*)d_in[4];
  // d_in[5], d_in[6] (Wr, br) are dead: H == 0 so R is never used
  const float* Wh     = (const float*)d_in[7];
  const float* bh     = (const float*)d_in[8];
  const float* Lz_w   = (const float*)d_in[9];
  const float* Lz_b   = (const float*)d_in[10];
  // d_in[11], d_in[12] (Lr) dead
  const float* Lh_w   = (const float*)d_in[13];
  const float* Lh_b   = (const float*)d_in[14];
  const float* W_out  = (const float*)d_in[15];
  const float* b_out  = (const float*)d_in[16];
  float* out = (float*)d_out;

  // workspace layout (floats): deg[N] | acc[N*64] | Mz[2048] Mh[2048] Bz[64] Bh[64]
  float* deg = (float*)d_ws;
  float* acc = deg + NN;
  float* Mz  = acc + (size_t)NN * HID;
  float* Mh  = Mz + IN_C * HID;
  float* Bz  = Mh + IN_C * HID;
  float* Bh  = Bz + HID;
  // y [N,32] lives in d_out (freed before out_kernel writes)
  float* y = out;

  prep_kernel<<<dim3(IN_C + 1, 2), 64, 0, stream>>>(Wz, bz, Lz_w, Lz_b, Wh, bh,
                                                    Lh_w, Lh_b, Mz, Bz, Mh, Bh);
  hipMemsetAsync(acc, 0, (size_t)NN * HID * sizeof(float), stream);

  const int degBlocks = (NN + 255) / 256;
  const int eBlocks = (EE + 255) / 256;
  const int scatBlocks = (EE * 8 + 255) / 256;
  const int denseBlocks = (NN * HID + 255) / 256;

  for (int t = 0; t < TT; ++t) {
    const float* xt  = x + (size_t)t * NN * IN_C;
    const int*   st  = ei + (size_t)t * 2 * EE;
    const int*   dt  = st + EE;
    const float* wt  = ew + (size_t)t * EE;

    deg_init_kernel<<<degBlocks, 256, 0, stream>>>(deg);
    hipMemsetAsync(y, 0, (size_t)NN * IN_C * sizeof(float), stream);
    deg_kernel<<<eBlocks, 256, 0, stream>>>(dt, wt, deg);
    scatter_kernel<<<scatBlocks, 256, 0, stream>>>(st, dt, wt, deg, xt, y);
    dense_kernel<<<denseBlocks, 256, 0, stream>>>(xt, y, deg, Mz, Bz, Mh, Bh, acc);
  }

  out_kernel<<<(NN * OUT_C + 255) / 256, 256, 0, stream>>>(acc, W_out, b_out, out);
}

// Round 2
// 3833.620 us; speedup vs baseline: 1.3210x; 1.3210x over previous
//
#include <hip/hip_runtime.h>

#define NN 50000
#define TT 12
#define EE 800000
#define IN_C 32
#define HID 64
#define OUT_C 32
#define SCAN_T 1024
#define CHUNK ((NN + SCAN_T - 1) / SCAN_T)  // 49
#define NPB 8                               // nodes per gather block

// ---------------- precompute folded gate matrices ----------------
// Mz = Wz @ Lz_w[:64]   (32x64),  Bz = bz @ Lz_w[:64] + Lz_b  (64)
// Mh = Wh @ Lh_w[:64]   (32x64),  Bh = bh @ Lh_w[:64] + Lh_b  (64)
__global__ __launch_bounds__(64) void prep_kernel(
    const float* __restrict__ Wz, const float* __restrict__ bz,
    const float* __restrict__ Lzw, const float* __restrict__ Lzb,
    const float* __restrict__ Wh, const float* __restrict__ bh,
    const float* __restrict__ Lhw, const float* __restrict__ Lhb,
    float* __restrict__ Mz, float* __restrict__ Bz,
    float* __restrict__ Mh, float* __restrict__ Bh) {
  const int j = threadIdx.x;  // 0..63 output col
  const int i = blockIdx.x;   // 0..32 (32 => bias row)
  const int h = blockIdx.y;   // 0 => z, 1 => h
  const float* W  = h ? Wh  : Wz;
  const float* b  = h ? bh  : bz;
  const float* L  = h ? Lhw : Lzw;
  const float* Lb = h ? Lhb : Lzb;
  float* M = h ? Mh : Mz;
  float* B = h ? Bh : Bz;
  if (i < IN_C) {
    float v = 0.f;
    for (int k = 0; k < HID; ++k) v += W[i * HID + k] * L[k * HID + j];
    M[i * HID + j] = v;
  } else {
    float v = Lb[j];
    for (int k = 0; k < HID; ++k) v += b[k] * L[k * HID + j];
    B[j] = v;
  }
}

// deg[n] = 1 (self-loop), cursor[n] = 0 (edge count)
__global__ __launch_bounds__(256) void init_kernel(float* __restrict__ deg,
                                                   int* __restrict__ cursor) {
  int n = blockIdx.x * 256 + threadIdx.x;
  if (n < NN) { deg[n] = 1.0f; cursor[n] = 0; }
}

// per edge: count[dst]++, deg[dst] += w
__global__ __launch_bounds__(256) void hist_kernel(const int* __restrict__ dst,
                                                   const float* __restrict__ w,
                                                   int* __restrict__ cursor,
                                                   float* __restrict__ deg) {
  int e = blockIdx.x * 256 + threadIdx.x;
  if (e < EE) {
    int d = dst[e];
    atomicAdd(&cursor[d], 1);
    atomicAdd(&deg[d], w[e]);
  }
}

// exclusive prefix sum of cursor(=counts) -> off, and rewrite cursor = off
__global__ __launch_bounds__(SCAN_T) void scan_kernel(int* __restrict__ cursor,
                                                      int* __restrict__ off) {
  __shared__ int part[SCAN_T];
  int t = threadIdx.x;
  int base = t * CHUNK;
  int sum = 0;
  for (int i = 0; i < CHUNK; ++i) {
    int idx = base + i;
    if (idx < NN) sum += cursor[idx];
  }
  part[t] = sum;
  __syncthreads();
  for (int o = 1; o < SCAN_T; o <<= 1) {
    int v = (t >= o) ? part[t - o] : 0;
    __syncthreads();
    part[t] += v;
    __syncthreads();
  }
  int run = (t == 0) ? 0 : part[t - 1];
  for (int i = 0; i < CHUNK; ++i) {
    int idx = base + i;
    if (idx < NN) {
      int cv = cursor[idx];
      off[idx] = run;
      cursor[idx] = run;
      run += cv;
    }
  }
  if (t == SCAN_T - 1) off[NN] = run;  // == EE
}

// per edge: place (src, norm) into CSR slot of dst
__global__ __launch_bounds__(256) void fill_kernel(const int* __restrict__ src,
                                                   const int* __restrict__ dst,
                                                   const float* __restrict__ w,
                                                   const float* __restrict__ deg,
                                                   int* __restrict__ cursor,
                                                   int* __restrict__ csr_src,
                                                   float* __restrict__ csr_norm) {
  int e = blockIdx.x * 256 + threadIdx.x;
  if (e >= EE) return;
  int s = src[e], d = dst[e];
  float nv = rsqrtf(deg[s]) * w[e] * rsqrtf(deg[d]);
  int pos = atomicAdd(&cursor[d], 1);
  csr_src[pos] = s;
  csr_norm[pos] = nv;
}

// fused gather + gate:  yt[c] = x[n][c]/deg[n] + sum_e norm_e * x[src_e][c]
// acc[n][j] += (1 - sigmoid(Bz[j] + yt.Mz[:,j])) * tanh(Bh[j] + yt.Mh[:,j])
__global__ __launch_bounds__(256) void gather_dense_kernel(
    const float* __restrict__ x, const float* __restrict__ deg,
    const int* __restrict__ off, const int* __restrict__ csr_src,
    const float* __restrict__ csr_norm,
    const float* __restrict__ Mz, const float* __restrict__ Bz,
    const float* __restrict__ Mh, const float* __restrict__ Bh,
    float* __restrict__ acc) {
  __shared__ float sMz[IN_C * HID], sMh[IN_C * HID], sBz[HID], sBh[HID];
  __shared__ float yt[NPB][IN_C];
  int t = threadIdx.x;
  for (int i = t; i < IN_C * HID; i += 256) {
    sMz[i] = Mz[i];
    sMh[i] = Mh[i];
  }
  if (t < HID) { sBz[t] = Bz[t]; sBh[t] = Bh[t]; }

  int nb = blockIdx.x * NPB;
  // --- gather phase: 32 threads (one per channel) per node ---
  int ln = t >> 5;
  int c = t & 31;
  int n = nb + ln;
  if (n < NN) {
    int e0 = off[n], e1 = off[n + 1];
    float v = x[(size_t)n * IN_C + c] / deg[n];  // self-loop: dinv^2 = 1/deg
    for (int e = e0; e < e1; ++e) {
      int s = csr_src[e];
      float nv = csr_norm[e];
      v += nv * x[(size_t)s * IN_C + c];
    }
    yt[ln][c] = v;
  }
  __syncthreads();
  // --- gate phase: 64 threads per node, 4 nodes per round, 2 rounds ---
  int j = t & 63;
  int lb = t >> 6;  // 0..3
  for (int r = 0; r < 2; ++r) {
    int lnode = lb + r * 4;
    int n2 = nb + lnode;
    if (n2 < NN) {
      float za = sBz[j], ha = sBh[j];
#pragma unroll
      for (int cc = 0; cc < IN_C; ++cc) {
        float yv = yt[lnode][cc];
        za += yv * sMz[cc * HID + j];
        ha += yv * sMh[cc * HID + j];
      }
      float z = 1.0f / (1.0f + expf(-za));
      float th = tanhf(ha);
      acc[(size_t)n2 * HID + j] += (1.0f - z) * th;
    }
  }
}

// out[n][o] = (acc[n]/T) . W_out[:,o] + b_out[o]
__global__ __launch_bounds__(256) void out_kernel(const float* __restrict__ acc,
                                                  const float* __restrict__ W_out,
                                                  const float* __restrict__ b_out,
                                                  float* __restrict__ out) {
  __shared__ float sW[HID * OUT_C], sB[OUT_C];
  for (int i = threadIdx.x; i < HID * OUT_C; i += 256) sW[i] = W_out[i];
  if (threadIdx.x < OUT_C) sB[threadIdx.x] = b_out[threadIdx.x];
  __syncthreads();
  unsigned tid = blockIdx.x * 256u + threadIdx.x;
  unsigned n = tid >> 5;
  int o = tid & 31;
  if (n >= NN) return;
  const float* ar = acc + (size_t)n * HID;
  float v = 0.f;
#pragma unroll
  for (int k = 0; k < HID; ++k) v += ar[k] * sW[k * OUT_C + o];
  out[(size_t)n * OUT_C + o] = v * (1.0f / (float)TT) + sB[o];
}

extern "C" void kernel_launch(void* const* d_in, const int* in_sizes, int n_in,
                              void* d_out, int out_size, void* d_ws, size_t ws_size,
                              hipStream_t stream) {
  const float* x     = (const float*)d_in[0];  // [T,N,32]
  const int*   ei    = (const int*)d_in[1];    // [T,2,E]
  const float* ew    = (const float*)d_in[2];  // [T,E]
  const float* Wz    = (const float*)d_in[3];
  const float* bz    = (const float*)d_in[4];
  // d_in[5..6] (Wr,br) dead: H==0 so R unused
  const float* Wh    = (const float*)d_in[7];
  const float* bh    = (const float*)d_in[8];
  const float* Lz_w  = (const float*)d_in[9];
  const float* Lz_b  = (const float*)d_in[10];
  // d_in[11..12] (Lr) dead
  const float* Lh_w  = (const float*)d_in[13];
  const float* Lh_b  = (const float*)d_in[14];
  const float* W_out = (const float*)d_in[15];
  const float* b_out = (const float*)d_in[16];
  float* out = (float*)d_out;

  // ws layout: deg[N] f | acc[N*64] f | Mz[2048] Mh[2048] Bz[64] Bh[64] f
  //          | off[N+1] i | cursor[N] i            (~13.4 MB total)
  float* deg = (float*)d_ws;
  float* acc = deg + NN;
  float* Mz  = acc + (size_t)NN * HID;
  float* Mh  = Mz + IN_C * HID;
  float* Bz  = Mh + IN_C * HID;
  float* Bh  = Bz + HID;
  int* off    = (int*)(Bh + HID);
  int* cursor = off + (NN + 1);
  // CSR arrays live in d_out (6.4 MB), dead by the time out_kernel writes
  int*   csr_src  = (int*)out;
  float* csr_norm = (float*)(csr_src + EE);

  prep_kernel<<<dim3(IN_C + 1, 2), 64, 0, stream>>>(Wz, bz, Lz_w, Lz_b, Wh, bh,
                                                    Lh_w, Lh_b, Mz, Bz, Mh, Bh);
  hipMemsetAsync(acc, 0, (size_t)NN * HID * sizeof(float), stream);

  const int nBlocks = (NN + 255) / 256;
  const int eBlocks = (EE + 255) / 256;
  const int gBlocks = (NN + NPB - 1) / NPB;

  for (int t = 0; t < TT; ++t) {
    const float* xt = x + (size_t)t * NN * IN_C;
    const int*   st = ei + (size_t)t * 2 * EE;
    const int*   dt = st + EE;
    const float* wt = ew + (size_t)t * EE;

    init_kernel<<<nBlocks, 256, 0, stream>>>(deg, cursor);
    hist_kernel<<<eBlocks, 256, 0, stream>>>(dt, wt, cursor, deg);
    scan_kernel<<<1, SCAN_T, 0, stream>>>(cursor, off);
    fill_kernel<<<eBlocks, 256, 0, stream>>>(st, dt, wt, deg, cursor, csr_src, csr_norm);
    gather_dense_kernel<<<gBlocks, 256, 0, stream>>>(xt, deg, off, csr_src, csr_norm,
                                                     Mz, Bz, Mh, Bh, acc);
  }

  out_kernel<<<(NN * OUT_C + 255) / 256, 256, 0, stream>>>(acc, W_out, b_out, out);
}

// Round 3
// 2430.138 us; speedup vs baseline: 2.0839x; 1.5775x over previous
//
#include <hip/hip_runtime.h>

#define NN 50000
#define TT 12
#define EE 800000
#define IN_C 32
#define HID 64
#define OUT_C 32
#define SCAN_B 256
#define NBLK ((NN + SCAN_B - 1) / SCAN_B)  // 196
#define NPB 8                              // nodes per gather block

// ---------------- precompute folded gate matrices ----------------
// Mz = Wz @ Lz_w[:64]   (32x64),  Bz = bz @ Lz_w[:64] + Lz_b  (64)
// Mh = Wh @ Lh_w[:64]   (32x64),  Bh = bh @ Lh_w[:64] + Lh_b  (64)
__global__ __launch_bounds__(64) void prep_kernel(
    const float* __restrict__ Wz, const float* __restrict__ bz,
    const float* __restrict__ Lzw, const float* __restrict__ Lzb,
    const float* __restrict__ Wh, const float* __restrict__ bh,
    const float* __restrict__ Lhw, const float* __restrict__ Lhb,
    float* __restrict__ Mz, float* __restrict__ Bz,
    float* __restrict__ Mh, float* __restrict__ Bh) {
  const int j = threadIdx.x;  // 0..63 output col
  const int i = blockIdx.x;   // 0..32 (32 => bias row)
  const int h = blockIdx.y;   // 0 => z, 1 => h
  const float* W  = h ? Wh  : Wz;
  const float* b  = h ? bh  : bz;
  const float* L  = h ? Lhw : Lzw;
  const float* Lb = h ? Lhb : Lzb;
  float* M = h ? Mh : Mz;
  float* B = h ? Bh : Bz;
  if (i < IN_C) {
    float v = 0.f;
    for (int k = 0; k < HID; ++k) v += W[i * HID + k] * L[k * HID + j];
    M[i * HID + j] = v;
  } else {
    float v = Lb[j];
    for (int k = 0; k < HID; ++k) v += b[k] * L[k * HID + j];
    B[j] = v;
  }
}

// deg[n] = 1 (self-loop), cursor[n] = 0 (edge count)
__global__ __launch_bounds__(256) void init_kernel(float* __restrict__ deg,
                                                   int* __restrict__ cursor) {
  int n = blockIdx.x * 256 + threadIdx.x;
  if (n < NN) { deg[n] = 1.0f; cursor[n] = 0; }
}

// per edge: count[dst]++, deg[dst] += w
__global__ __launch_bounds__(256) void hist_kernel(const int* __restrict__ dst,
                                                   const float* __restrict__ w,
                                                   int* __restrict__ cursor,
                                                   float* __restrict__ deg) {
  int e = blockIdx.x * 256 + threadIdx.x;
  if (e < EE) {
    int d = dst[e];
    atomicAdd(&cursor[d], 1);
    atomicAdd(&deg[d], w[e]);
  }
}

// per-256-node-chunk sums of counts -> bsum[NBLK]
__global__ __launch_bounds__(SCAN_B) void partial_kernel(const int* __restrict__ counts,
                                                         int* __restrict__ bsum) {
  __shared__ int s[SCAN_B];
  int t = threadIdx.x;
  int idx = blockIdx.x * SCAN_B + t;
  s[t] = (idx < NN) ? counts[idx] : 0;
  __syncthreads();
  for (int o = SCAN_B / 2; o > 0; o >>= 1) {
    if (t < o) s[t] += s[t + o];
    __syncthreads();
  }
  if (t == 0) bsum[blockIdx.x] = s[0];
}

// per block: boff = excl-sum(bsum[:b]); local excl scan of 256 counts;
// off[n] = cursor[n] = boff + local; last block writes off[NN]
__global__ __launch_bounds__(SCAN_B) void offs_kernel(const int* __restrict__ bsum,
                                                      int* __restrict__ cursor,
                                                      int* __restrict__ off) {
  __shared__ int sb[SCAN_B];
  __shared__ int sc[SCAN_B];
  int b = blockIdx.x, t = threadIdx.x;
  sb[t] = (t < NBLK) ? bsum[t] : 0;
  __syncthreads();
  // inclusive Hillis-Steele scan over block partials
  for (int o = 1; o < SCAN_B; o <<= 1) {
    int v = (t >= o) ? sb[t - o] : 0;
    __syncthreads();
    sb[t] += v;
    __syncthreads();
  }
  int boff = (b == 0) ? 0 : sb[b - 1];
  int idx = b * SCAN_B + t;
  int cv = (idx < NN) ? cursor[idx] : 0;
  sc[t] = cv;
  __syncthreads();
  // inclusive scan of local counts
  for (int o = 1; o < SCAN_B; o <<= 1) {
    int v = (t >= o) ? sc[t - o] : 0;
    __syncthreads();
    sc[t] += v;
    __syncthreads();
  }
  int excl = sc[t] - cv;  // exclusive
  if (idx < NN) {
    int o2 = boff + excl;
    off[idx] = o2;
    cursor[idx] = o2;
  }
  if (b == NBLK - 1 && t == SCAN_B - 1) off[NN] = boff + sc[t];  // == EE
}

// per edge: place (src, norm) into CSR slot of dst
__global__ __launch_bounds__(256) void fill_kernel(const int* __restrict__ src,
                                                   const int* __restrict__ dst,
                                                   const float* __restrict__ w,
                                                   const float* __restrict__ deg,
                                                   int* __restrict__ cursor,
                                                   int* __restrict__ csr_src,
                                                   float* __restrict__ csr_norm) {
  int e = blockIdx.x * 256 + threadIdx.x;
  if (e >= EE) return;
  int s = src[e], d = dst[e];
  float nv = rsqrtf(deg[s]) * w[e] * rsqrtf(deg[d]);
  int pos = atomicAdd(&cursor[d], 1);
  csr_src[pos] = s;
  csr_norm[pos] = nv;
}

// fused gather + gate:  yt[c] = x[n][c]/deg[n] + sum_e norm_e * x[src_e][c]
// acc[n][j] += (1 - sigmoid(Bz[j] + yt.Mz[:,j])) * tanh(Bh[j] + yt.Mh[:,j])
__global__ __launch_bounds__(256) void gather_dense_kernel(
    const float* __restrict__ x, const float* __restrict__ deg,
    const int* __restrict__ off, const int* __restrict__ csr_src,
    const float* __restrict__ csr_norm,
    const float* __restrict__ Mz, const float* __restrict__ Bz,
    const float* __restrict__ Mh, const float* __restrict__ Bh,
    float* __restrict__ acc) {
  __shared__ float sMz[IN_C * HID], sMh[IN_C * HID], sBz[HID], sBh[HID];
  __shared__ float yt[NPB][IN_C];
  int t = threadIdx.x;
  for (int i = t; i < IN_C * HID; i += 256) {
    sMz[i] = Mz[i];
    sMh[i] = Mh[i];
  }
  if (t < HID) { sBz[t] = Bz[t]; sBh[t] = Bh[t]; }

  int nb = blockIdx.x * NPB;
  // --- gather phase: 32 threads (one per channel) per node ---
  int ln = t >> 5;
  int c = t & 31;
  int n = nb + ln;
  if (n < NN) {
    int e0 = off[n], e1 = off[n + 1];
    float v = x[(size_t)n * IN_C + c] / deg[n];  // self-loop: dinv^2 = 1/deg
    for (int e = e0; e < e1; ++e) {
      int s = csr_src[e];
      float nv = csr_norm[e];
      v += nv * x[(size_t)s * IN_C + c];
    }
    yt[ln][c] = v;
  }
  __syncthreads();
  // --- gate phase: 64 threads per node, 4 nodes per round, 2 rounds ---
  int j = t & 63;
  int lb = t >> 6;  // 0..3
  for (int r = 0; r < 2; ++r) {
    int lnode = lb + r * 4;
    int n2 = nb + lnode;
    if (n2 < NN) {
      float za = sBz[j], ha = sBh[j];
#pragma unroll
      for (int cc = 0; cc < IN_C; ++cc) {
        float yv = yt[lnode][cc];
        za += yv * sMz[cc * HID + j];
        ha += yv * sMh[cc * HID + j];
      }
      float z = 1.0f / (1.0f + expf(-za));
      float th = tanhf(ha);
      acc[(size_t)n2 * HID + j] += (1.0f - z) * th;
    }
  }
}

// out[n][o] = (acc[n]/T) . W_out[:,o] + b_out[o]
__global__ __launch_bounds__(256) void out_kernel(const float* __restrict__ acc,
                                                  const float* __restrict__ W_out,
                                                  const float* __restrict__ b_out,
                                                  float* __restrict__ out) {
  __shared__ float sW[HID * OUT_C], sB[OUT_C];
  for (int i = threadIdx.x; i < HID * OUT_C; i += 256) sW[i] = W_out[i];
  if (threadIdx.x < OUT_C) sB[threadIdx.x] = b_out[threadIdx.x];
  __syncthreads();
  unsigned tid = blockIdx.x * 256u + threadIdx.x;
  unsigned n = tid >> 5;
  int o = tid & 31;
  if (n >= NN) return;
  const float* ar = acc + (size_t)n * HID;
  float v = 0.f;
#pragma unroll
  for (int k = 0; k < HID; ++k) v += ar[k] * sW[k * OUT_C + o];
  out[(size_t)n * OUT_C + o] = v * (1.0f / (float)TT) + sB[o];
}

extern "C" void kernel_launch(void* const* d_in, const int* in_sizes, int n_in,
                              void* d_out, int out_size, void* d_ws, size_t ws_size,
                              hipStream_t stream) {
  const float* x     = (const float*)d_in[0];  // [T,N,32]
  const int*   ei    = (const int*)d_in[1];    // [T,2,E]
  const float* ew    = (const float*)d_in[2];  // [T,E]
  const float* Wz    = (const float*)d_in[3];
  const float* bz    = (const float*)d_in[4];
  // d_in[5..6] (Wr,br) dead: H==0 so R unused
  const float* Wh    = (const float*)d_in[7];
  const float* bh    = (const float*)d_in[8];
  const float* Lz_w  = (const float*)d_in[9];
  const float* Lz_b  = (const float*)d_in[10];
  // d_in[11..12] (Lr) dead
  const float* Lh_w  = (const float*)d_in[13];
  const float* Lh_b  = (const float*)d_in[14];
  const float* W_out = (const float*)d_in[15];
  const float* b_out = (const float*)d_in[16];
  float* out = (float*)d_out;

  // ws layout: deg[N] f | acc[N*64] f | Mz[2048] Mh[2048] Bz[64] Bh[64] f
  //          | off[N+1] i | cursor[N] i | bsum[NBLK] i        (~13.4 MB)
  float* deg = (float*)d_ws;
  float* acc = deg + NN;
  float* Mz  = acc + (size_t)NN * HID;
  float* Mh  = Mz + IN_C * HID;
  float* Bz  = Mh + IN_C * HID;
  float* Bh  = Bz + HID;
  int* off    = (int*)(Bh + HID);
  int* cursor = off + (NN + 1);
  int* bsum   = cursor + NN;
  // CSR arrays live in d_out (6.4 MB), dead by the time out_kernel writes
  int*   csr_src  = (int*)out;
  float* csr_norm = (float*)(csr_src + EE);

  prep_kernel<<<dim3(IN_C + 1, 2), 64, 0, stream>>>(Wz, bz, Lz_w, Lz_b, Wh, bh,
                                                    Lh_w, Lh_b, Mz, Bz, Mh, Bh);
  hipMemsetAsync(acc, 0, (size_t)NN * HID * sizeof(float), stream);

  const int nBlocks = (NN + 255) / 256;
  const int eBlocks = (EE + 255) / 256;
  const int gBlocks = (NN + NPB - 1) / NPB;

  for (int t = 0; t < TT; ++t) {
    const float* xt = x + (size_t)t * NN * IN_C;
    const int*   st = ei + (size_t)t * 2 * EE;
    const int*   dt = st + EE;
    const float* wt = ew + (size_t)t * EE;

    init_kernel<<<nBlocks, 256, 0, stream>>>(deg, cursor);
    hist_kernel<<<eBlocks, 256, 0, stream>>>(dt, wt, cursor, deg);
    partial_kernel<<<NBLK, SCAN_B, 0, stream>>>(cursor, bsum);
    offs_kernel<<<NBLK, SCAN_B, 0, stream>>>(bsum, cursor, off);
    fill_kernel<<<eBlocks, 256, 0, stream>>>(st, dt, wt, deg, cursor, csr_src, csr_norm);
    gather_dense_kernel<<<gBlocks, 256, 0, stream>>>(xt, deg, off, csr_src, csr_norm,
                                                     Mz, Bz, Mh, Bh, acc);
  }

  out_kernel<<<(NN * OUT_C + 255) / 256, 256, 0, stream>>>(acc, W_out, b_out, out);
}

// Round 4
// 1829.638 us; speedup vs baseline: 2.7678x; 1.3282x over previous
//
#include <hip/hip_runtime.h>

#define NN 50000
#define TT 12
#define EE 800000
#define IN_C 32
#define HID 64
#define OUT_C 32
#define SCAN_B 256
#define NBLK ((NN + SCAN_B - 1) / SCAN_B)  // 196
#define EBLK ((EE + 255) / 256)            // 3125
#define GNPB 4                             // nodes per gather block (NN % 4 == 0)
#define WFIX 8388608.0f                    // 2^23 fixed-point scale for weight sums

// ---------------- precompute folded gate matrices ----------------
// Mz = Wz @ Lz_w[:64] (32x64), Bz = bz @ Lz_w[:64] + Lz_b (64); same for h.
__global__ __launch_bounds__(64) void prep_kernel(
    const float* __restrict__ Wz, const float* __restrict__ bz,
    const float* __restrict__ Lzw, const float* __restrict__ Lzb,
    const float* __restrict__ Wh, const float* __restrict__ bh,
    const float* __restrict__ Lhw, const float* __restrict__ Lhb,
    float* __restrict__ Mz, float* __restrict__ Bz,
    float* __restrict__ Mh, float* __restrict__ Bh) {
  const int j = threadIdx.x;  // 0..63 output col
  const int i = blockIdx.x;   // 0..32 (32 => bias row)
  const int h = blockIdx.y;   // 0 => z, 1 => h
  const float* W  = h ? Wh  : Wz;
  const float* b  = h ? bh  : bz;
  const float* L  = h ? Lhw : Lzw;
  const float* Lb = h ? Lhb : Lzb;
  float* M = h ? Mh : Mz;
  float* B = h ? Bh : Bz;
  if (i < IN_C) {
    float v = 0.f;
    for (int k = 0; k < HID; ++k) v += W[i * HID + k] * L[k * HID + j];
    M[i * HID + j] = v;
  } else {
    float v = Lb[j];
    for (int k = 0; k < HID; ++k) v += b[k] * L[k * HID + j];
    B[j] = v;
  }
}

// one packed atomic per edge: hi32 = count, lo32 = round(w * 2^23)
// (deg <= ~64 per node, so lo sum < 2^29 — no overflow into hi word)
__global__ __launch_bounds__(256) void hist_kernel(const int* __restrict__ ei,
                                                   const float* __restrict__ ew,
                                                   unsigned long long* __restrict__ pcA,
                                                   int tbase) {
  int tl = blockIdx.y;
  const int* dst = ei + (size_t)(tbase + tl) * 2 * EE + EE;
  const float* w = ew + (size_t)(tbase + tl) * EE;
  unsigned long long* pc = pcA + (size_t)tl * NN;
  int e = blockIdx.x * 256 + threadIdx.x;
  if (e < EE) {
    unsigned int wf = __float2uint_rn(w[e] * WFIX);
    atomicAdd(&pc[dst[e]], (1ull << 32) | (unsigned long long)wf);
  }
}

// per-256-node-chunk count sums -> bsum
__global__ __launch_bounds__(SCAN_B) void partial_kernel(
    const unsigned long long* __restrict__ pcA, int* __restrict__ bsumA) {
  const unsigned long long* pc = pcA + (size_t)blockIdx.y * NN;
  int* bsum = bsumA + (size_t)blockIdx.y * NBLK;
  __shared__ int s[SCAN_B];
  int t = threadIdx.x;
  int idx = blockIdx.x * SCAN_B + t;
  s[t] = (idx < NN) ? (int)(pc[idx] >> 32) : 0;
  __syncthreads();
  for (int o = SCAN_B / 2; o > 0; o >>= 1) {
    if (t < o) s[t] += s[t + o];
    __syncthreads();
  }
  if (t == 0) bsum[blockIdx.x] = s[0];
}

// per block: scan block partials for base, local scan of 256 counts;
// writes off[n], cursor[n], and deg[n] = 1 + fixed->float weight sum
__global__ __launch_bounds__(SCAN_B) void offs_kernel(
    const int* __restrict__ bsumA, const unsigned long long* __restrict__ pcA,
    int* __restrict__ cursorA, int* __restrict__ offA, float* __restrict__ degA) {
  int tl = blockIdx.y;
  const int* bsum = bsumA + (size_t)tl * NBLK;
  const unsigned long long* pc = pcA + (size_t)tl * NN;
  int* cursor = cursorA + (size_t)tl * NN;
  int* off = offA + (size_t)tl * (NN + 1);
  float* deg = degA + (size_t)tl * NN;
  __shared__ int sb[SCAN_B];
  __shared__ int sc[SCAN_B];
  int b = blockIdx.x, t = threadIdx.x;
  sb[t] = (t < NBLK) ? bsum[t] : 0;
  __syncthreads();
  for (int o = 1; o < SCAN_B; o <<= 1) {
    int v = (t >= o) ? sb[t - o] : 0;
    __syncthreads();
    sb[t] += v;
    __syncthreads();
  }
  int boff = (b == 0) ? 0 : sb[b - 1];
  int idx = b * SCAN_B + t;
  unsigned long long p = (idx < NN) ? pc[idx] : 0ull;
  int cv = (int)(p >> 32);
  sc[t] = cv;
  __syncthreads();
  for (int o = 1; o < SCAN_B; o <<= 1) {
    int v = (t >= o) ? sc[t - o] : 0;
    __syncthreads();
    sc[t] += v;
    __syncthreads();
  }
  if (idx < NN) {
    int o2 = boff + sc[t] - cv;  // exclusive
    off[idx] = o2;
    cursor[idx] = o2;
    deg[idx] = 1.0f + (float)(unsigned int)p * (1.0f / WFIX);
  }
  if (b == NBLK - 1 && t == SCAN_B - 1) off[NN] = boff + sc[t];  // == EE
}

// per edge: place (src, norm) into CSR slot of dst
__global__ __launch_bounds__(256) void fill_kernel(const int* __restrict__ ei,
                                                   const float* __restrict__ ew,
                                                   const float* __restrict__ degA,
                                                   int* __restrict__ cursorA,
                                                   int2* __restrict__ csrA,
                                                   int tbase) {
  int tl = blockIdx.y;
  const int* src = ei + (size_t)(tbase + tl) * 2 * EE;
  const int* dst = src + EE;
  const float* w = ew + (size_t)(tbase + tl) * EE;
  const float* deg = degA + (size_t)tl * NN;
  int* cursor = cursorA + (size_t)tl * NN;
  int2* csr = csrA + (size_t)tl * EE;
  int e = blockIdx.x * 256 + threadIdx.x;
  if (e >= EE) return;
  int s = src[e], d = dst[e];
  float nv = rsqrtf(deg[s]) * w[e] * rsqrtf(deg[d]);
  int pos = atomicAdd(&cursor[d], 1);
  csr[pos] = make_int2(s, __float_as_int(nv));
}

// mega gather+gate: one wave per node; loops over nt timesteps in-thread,
// accumulating the gate output in a register. yt tile is wave-private LDS
// (ln == wave id), so no barriers inside the t-loop.
__global__ __launch_bounds__(256) void gather_dense_kernel(
    const float* __restrict__ x, const float* __restrict__ degA,
    const int* __restrict__ offA, const int2* __restrict__ csrA,
    const float* __restrict__ Mz, const float* __restrict__ Bz,
    const float* __restrict__ Mh, const float* __restrict__ Bh,
    float* __restrict__ acc, int tbase, int nt) {
  __shared__ float sMz[IN_C * HID], sMh[IN_C * HID], sBz[HID], sBh[HID];
  __shared__ float yt[GNPB][IN_C];
  int t = threadIdx.x;
  for (int i = t; i < IN_C * HID; i += 256) {
    sMz[i] = Mz[i];
    sMh[i] = Mh[i];
  }
  if (t < HID) { sBz[t] = Bz[t]; sBh[t] = Bh[t]; }
  __syncthreads();

  int ln = t >> 6;        // wave id == local node
  int c  = t & 31;        // channel
  int h  = (t >> 5) & 1;  // edge half
  int j  = t & 63;        // gate column
  int n  = blockIdx.x * GNPB + ln;  // NN % GNPB == 0, no tail
  float accr = 0.f;

  for (int tl = 0; tl < nt; ++tl) {
    const float* xt = x + (size_t)(tbase + tl) * NN * IN_C;
    const float* deg = degA + (size_t)tl * NN;
    const int* off = offA + (size_t)tl * (NN + 1);
    const int2* csr = csrA + (size_t)tl * EE;
    int e0 = off[n], e1 = off[n + 1];
    float v = (h == 0) ? xt[(size_t)n * IN_C + c] / deg[n] : 0.f;
    for (int e = e0 + h; e < e1; e += 2) {
      int2 sv = csr[e];
      v += __int_as_float(sv.y) * xt[(size_t)sv.x * IN_C + c];
    }
    v += __shfl_xor(v, 32);
    if (h == 0) yt[ln][c] = v;  // wave-private; same-wave DS ops are in-order
    float za = sBz[j], ha = sBh[j];
    const float* yrow = yt[ln];
#pragma unroll
    for (int cc = 0; cc < IN_C; cc += 4) {
      float4 yv = *(const float4*)(yrow + cc);
      za += yv.x * sMz[(cc + 0) * HID + j];
      ha += yv.x * sMh[(cc + 0) * HID + j];
      za += yv.y * sMz[(cc + 1) * HID + j];
      ha += yv.y * sMh[(cc + 1) * HID + j];
      za += yv.z * sMz[(cc + 2) * HID + j];
      ha += yv.z * sMh[(cc + 2) * HID + j];
      za += yv.w * sMz[(cc + 3) * HID + j];
      ha += yv.w * sMh[(cc + 3) * HID + j];
    }
    float z = 1.0f / (1.0f + expf(-za));
    accr += (1.0f - z) * tanhf(ha);
  }
  size_t ai = (size_t)n * HID + j;
  acc[ai] = (tbase == 0 ? 0.f : acc[ai]) + accr;
}

// out[n][o] = (acc[n]/T) . W_out[:,o] + b_out[o]
__global__ __launch_bounds__(256) void out_kernel(const float* __restrict__ acc,
                                                  const float* __restrict__ W_out,
                                                  const float* __restrict__ b_out,
                                                  float* __restrict__ out) {
  __shared__ float sW[HID * OUT_C], sB[OUT_C];
  for (int i = threadIdx.x; i < HID * OUT_C; i += 256) sW[i] = W_out[i];
  if (threadIdx.x < OUT_C) sB[threadIdx.x] = b_out[threadIdx.x];
  __syncthreads();
  unsigned tid = blockIdx.x * 256u + threadIdx.x;
  unsigned n = tid >> 5;
  int o = tid & 31;
  if (n >= NN) return;
  const float* ar = acc + (size_t)n * HID;
  float v = 0.f;
#pragma unroll
  for (int k = 0; k < HID; ++k) v += ar[k] * sW[k * OUT_C + o];
  out[(size_t)n * OUT_C + o] = v * (1.0f / (float)TT) + sB[o];
}

extern "C" void kernel_launch(void* const* d_in, const int* in_sizes, int n_in,
                              void* d_out, int out_size, void* d_ws, size_t ws_size,
                              hipStream_t stream) {
  const float* x     = (const float*)d_in[0];  // [T,N,32]
  const int*   ei    = (const int*)d_in[1];    // [T,2,E]
  const float* ew    = (const float*)d_in[2];  // [T,E]
  const float* Wz    = (const float*)d_in[3];
  const float* bz    = (const float*)d_in[4];
  // d_in[5..6] (Wr,br) dead: H==0 so R unused
  const float* Wh    = (const float*)d_in[7];
  const float* bh    = (const float*)d_in[8];
  const float* Lz_w  = (const float*)d_in[9];
  const float* Lz_b  = (const float*)d_in[10];
  // d_in[11..12] (Lr) dead
  const float* Lh_w  = (const float*)d_in[13];
  const float* Lh_b  = (const float*)d_in[14];
  const float* W_out = (const float*)d_in[15];
  const float* b_out = (const float*)d_in[16];
  float* out = (float*)d_out;

  // per-timestep scratch sizes (bytes)
  const size_t pcB   = (size_t)NN * 8;
  const size_t csrB  = (size_t)EE * 8;
  const size_t degB  = (size_t)NN * 4;
  const size_t offB  = (size_t)(NN + 1) * 4;
  const size_t curB  = (size_t)NN * 4;
  const size_t bsumB = (size_t)NBLK * 4;
  const size_t perT  = pcB + csrB + degB + offB + curB + bsumB;      // ~7.4 MB
  const size_t fixedB = (size_t)(2 * IN_C * HID + 2 * HID) * 4
                      + (size_t)NN * HID * 4;                         // ~12.8 MB

  int nt;
  bool csrInOut = false;
  if (ws_size >= fixedB + 12 * perT) {
    nt = 12;
  } else if (ws_size >= fixedB + perT) {
    nt = (int)((ws_size - fixedB) / perT);
    if (nt > 12) nt = 12;
  } else {
    nt = 1;           // csr lives in d_out (dead until out_kernel)
    csrInOut = true;
  }

  // workspace layout: 8-byte-aligned arrays first
  char* p = (char*)d_ws;
  unsigned long long* pc = (unsigned long long*)p; p += pcB * nt;
  int2* csr;
  if (!csrInOut) { csr = (int2*)p; p += csrB * nt; }
  else           { csr = (int2*)d_out; }
  float* deg   = (float*)p; p += degB * nt;
  int*  off    = (int*)p;   p += offB * nt;
  int*  cursor = (int*)p;   p += curB * nt;
  int*  bsum   = (int*)p;   p += bsumB * nt;
  float* Mz = (float*)p;
  float* Mh = Mz + IN_C * HID;
  float* Bz = Mh + IN_C * HID;
  float* Bh = Bz + HID;
  float* acc = Bh + HID;  // [N,64]

  prep_kernel<<<dim3(IN_C + 1, 2), 64, 0, stream>>>(Wz, bz, Lz_w, Lz_b, Wh, bh,
                                                    Lh_w, Lh_b, Mz, Bz, Mh, Bh);

  for (int tb = 0; tb < TT; tb += nt) {
    int cnt = (TT - tb < nt) ? (TT - tb) : nt;
    hipMemsetAsync(pc, 0, pcB * cnt, stream);
    hist_kernel<<<dim3(EBLK, cnt), 256, 0, stream>>>(ei, ew, pc, tb);
    partial_kernel<<<dim3(NBLK, cnt), SCAN_B, 0, stream>>>(pc, bsum);
    offs_kernel<<<dim3(NBLK, cnt), SCAN_B, 0, stream>>>(bsum, pc, cursor, off, deg);
    fill_kernel<<<dim3(EBLK, cnt), 256, 0, stream>>>(ei, ew, deg, cursor, csr, tb);
    gather_dense_kernel<<<NN / GNPB, 256, 0, stream>>>(x, deg, off, csr,
                                                       Mz, Bz, Mh, Bh, acc, tb, cnt);
  }

  out_kernel<<<(NN * OUT_C + 255) / 256, 256, 0, stream>>>(acc, W_out, b_out, out);
}

// Round 5
// 1484.367 us; speedup vs baseline: 3.4117x; 1.2326x over previous
//
#include <hip/hip_runtime.h>
#include <hip/hip_fp16.h>

#define NN 50000
#define TT 12
#define EE 800000
#define IN_C 32
#define HID 64
#define OUT_C 32
#define SCAN_B 256
#define NBLK ((NN + SCAN_B - 1) / SCAN_B)  // 196
#define EBLK ((EE + 255) / 256)            // 3125
#define GNPB 4                             // nodes per gather block
#define WFIX 65536.0f                      // 2^16 fixed-point for weight sums
#define XPAIRS ((size_t)TT * NN * 16)      // half2 elements in x

// ---------------- precompute folded gate matrices ----------------
// Mz = Wz @ Lz_w[:64] (32x64), Bz = bz @ Lz_w[:64] + Lz_b (64); same for h.
__global__ __launch_bounds__(64) void prep_kernel(
    const float* __restrict__ Wz, const float* __restrict__ bz,
    const float* __restrict__ Lzw, const float* __restrict__ Lzb,
    const float* __restrict__ Wh, const float* __restrict__ bh,
    const float* __restrict__ Lhw, const float* __restrict__ Lhb,
    float* __restrict__ Mz, float* __restrict__ Bz,
    float* __restrict__ Mh, float* __restrict__ Bh) {
  const int j = threadIdx.x;
  const int i = blockIdx.x;
  const int h = blockIdx.y;
  const float* W  = h ? Wh  : Wz;
  const float* b  = h ? bh  : bz;
  const float* L  = h ? Lhw : Lzw;
  const float* Lb = h ? Lhb : Lzb;
  float* M = h ? Mh : Mz;
  float* B = h ? Bh : Bz;
  if (i < IN_C) {
    float v = 0.f;
    for (int k = 0; k < HID; ++k) v += W[i * HID + k] * L[k * HID + j];
    M[i * HID + j] = v;
  } else {
    float v = Lb[j];
    for (int k = 0; k < HID; ++k) v += b[k] * L[k * HID + j];
    B[j] = v;
  }
}

// x [T,N,32] fp32 -> fp16 (pairs)
__global__ __launch_bounds__(256) void xconv_kernel(const float* __restrict__ x,
                                                    __half2* __restrict__ xh) {
  size_t i = (size_t)blockIdx.x * 256 + threadIdx.x;
  if (i < XPAIRS) {
    float2 f = ((const float2*)x)[i];
    xh[i] = __floats2half2_rn(f.x, f.y);
  }
}

// one 4B atomic per edge: bits 24..31 = count, bits 0..23 = round(w * 2^16)
__global__ __launch_bounds__(256) void hist_kernel(const int* __restrict__ ei,
                                                   const float* __restrict__ ew,
                                                   unsigned* __restrict__ pcA,
                                                   int tbase) {
  int tl = blockIdx.y;
  const int* dst = ei + (size_t)(tbase + tl) * 2 * EE + EE;
  const float* w = ew + (size_t)(tbase + tl) * EE;
  unsigned* pc = pcA + (size_t)tl * NN;
  int e = blockIdx.x * 256 + threadIdx.x;
  if (e < EE) {
    unsigned wf = __float2uint_rn(w[e] * WFIX);
    atomicAdd(&pc[dst[e]], (1u << 24) + wf);
  }
}

// per-256-node-chunk count sums -> bsum
__global__ __launch_bounds__(SCAN_B) void partial_kernel(
    const unsigned* __restrict__ pcA, int* __restrict__ bsumA) {
  const unsigned* pc = pcA + (size_t)blockIdx.y * NN;
  int* bsum = bsumA + (size_t)blockIdx.y * NBLK;
  __shared__ int s[SCAN_B];
  int t = threadIdx.x;
  int idx = blockIdx.x * SCAN_B + t;
  s[t] = (idx < NN) ? (int)(pc[idx] >> 24) : 0;
  __syncthreads();
  for (int o = SCAN_B / 2; o > 0; o >>= 1) {
    if (t < o) s[t] += s[t + o];
    __syncthreads();
  }
  if (t == 0) bsum[blockIdx.x] = s[0];
}

// scan block partials for base, local scan of 256 counts;
// writes off[n], cursor[n], dinv[n] = rsqrt(1 + wsum)
__global__ __launch_bounds__(SCAN_B) void offs_kernel(
    const int* __restrict__ bsumA, const unsigned* __restrict__ pcA,
    int* __restrict__ cursorA, int* __restrict__ offA, float* __restrict__ dinvA) {
  int tl = blockIdx.y;
  const int* bsum = bsumA + (size_t)tl * NBLK;
  const unsigned* pc = pcA + (size_t)tl * NN;
  int* cursor = cursorA + (size_t)tl * NN;
  int* off = offA + (size_t)tl * (NN + 1);
  float* dinv = dinvA + (size_t)tl * NN;
  __shared__ int sb[SCAN_B];
  __shared__ int sc[SCAN_B];
  int b = blockIdx.x, t = threadIdx.x;
  sb[t] = (t < NBLK) ? bsum[t] : 0;
  __syncthreads();
  for (int o = 1; o < SCAN_B; o <<= 1) {
    int v = (t >= o) ? sb[t - o] : 0;
    __syncthreads();
    sb[t] += v;
    __syncthreads();
  }
  int boff = (b == 0) ? 0 : sb[b - 1];
  int idx = b * SCAN_B + t;
  unsigned p = (idx < NN) ? pc[idx] : 0u;
  int cv = (int)(p >> 24);
  sc[t] = cv;
  __syncthreads();
  for (int o = 1; o < SCAN_B; o <<= 1) {
    int v = (t >= o) ? sc[t - o] : 0;
    __syncthreads();
    sc[t] += v;
    __syncthreads();
  }
  if (idx < NN) {
    int o2 = boff + sc[t] - cv;
    off[idx] = o2;
    cursor[idx] = o2;
    dinv[idx] = rsqrtf(1.0f + (float)(p & 0xFFFFFFu) * (1.0f / WFIX));
  }
  if (b == NBLK - 1 && t == SCAN_B - 1) off[NN] = boff + sc[t];  // == EE
}

// per edge: csr slot of dst <- {u16 src | fp16 (w * dinv[src]) << 16}
// (dinv[dst] folded into gather epilogue)
__global__ __launch_bounds__(256) void fill_kernel(const int* __restrict__ ei,
                                                   const float* __restrict__ ew,
                                                   const float* __restrict__ dinvA,
                                                   int* __restrict__ cursorA,
                                                   unsigned* __restrict__ csrA,
                                                   int tbase) {
  int tl = blockIdx.y;
  const int* src = ei + (size_t)(tbase + tl) * 2 * EE;
  const int* dst = src + EE;
  const float* w = ew + (size_t)(tbase + tl) * EE;
  const float* dinv = dinvA + (size_t)tl * NN;
  int* cursor = cursorA + (size_t)tl * NN;
  unsigned* csr = csrA + (size_t)tl * EE;
  int e = blockIdx.x * 256 + threadIdx.x;
  if (e >= EE) return;
  int s = src[e], d = dst[e];
  float np = w[e] * dinv[s];
  unsigned hb = (unsigned)__half_as_ushort(__float2half_rn(np));
  int pos = atomicAdd(&cursor[d], 1);
  csr[pos] = (unsigned)s | (hb << 16);
}

// mega gather+gate: one wave per node, t-loop in-thread, register acc.
// lane = g*16 + cp: g = edge group (4-way split), cp = channel pair.
__global__ __launch_bounds__(256) void gather_dense_kernel(
    const float* __restrict__ x, const __half2* __restrict__ xh,
    const float* __restrict__ dinvA, const int* __restrict__ offA,
    const unsigned* __restrict__ csrA,
    const float* __restrict__ Mz, const float* __restrict__ Bz,
    const float* __restrict__ Mh, const float* __restrict__ Bh,
    float* __restrict__ acc, int tbase, int nt) {
  __shared__ float sMz[IN_C * HID], sMh[IN_C * HID], sBz[HID], sBh[HID];
  __shared__ float yt[GNPB][IN_C];
  int t = threadIdx.x;
  for (int i = t; i < IN_C * HID; i += 256) {
    sMz[i] = Mz[i];
    sMh[i] = Mh[i];
  }
  if (t < HID) { sBz[t] = Bz[t]; sBh[t] = Bh[t]; }
  __syncthreads();

  int ln = t >> 6;          // wave id == local node
  int lane = t & 63;
  int g  = lane >> 4;       // edge group 0..3
  int cp = lane & 15;       // channel pair 0..15
  int j  = lane;            // gate column
  int n = blockIdx.x * GNPB + ln;  // NN % GNPB == 0
  float accr = 0.f;

  for (int tl = 0; tl < nt; ++tl) {
    const __half2* xht = xh + (size_t)(tbase + tl) * NN * 16;
    const float* dinv = dinvA + (size_t)tl * NN;
    const int* off = offA + (size_t)tl * (NN + 1);
    const unsigned* csr = csrA + (size_t)tl * EE;
    int e0 = off[n], e1 = off[n + 1];
    float vx = 0.f, vy = 0.f;
    for (int e = e0 + g; e < e1; e += 4) {
      unsigned u = csr[e];
      float nm = __half2float(__ushort_as_half((unsigned short)(u >> 16)));
      float2 xf = __half22float2(xht[(size_t)(u & 0xFFFFu) * 16 + cp]);
      vx += nm * xf.x;
      vy += nm * xf.y;
    }
    vx += __shfl_xor(vx, 16);
    vy += __shfl_xor(vy, 16);
    vx += __shfl_xor(vx, 32);
    vy += __shfl_xor(vy, 32);
    float dv = dinv[n];
    if (g == 0) {
      // self-loop from fp32 x for precision: yt = dv*(edge_sum + dv*x_n)
      const float* xt = x + (size_t)(tbase + tl) * NN * IN_C;
      float2 xs = ((const float2*)(xt + (size_t)n * IN_C))[cp];
      yt[ln][2 * cp]     = dv * (vx + dv * xs.x);
      yt[ln][2 * cp + 1] = dv * (vy + dv * xs.y);
    }
    // wave-private LDS: same-wave write->read is in-order, no barrier
    float za = sBz[j], ha = sBh[j];
    const float* yrow = yt[ln];
#pragma unroll
    for (int cc = 0; cc < IN_C; cc += 4) {
      float4 yv = *(const float4*)(yrow + cc);
      za += yv.x * sMz[(cc + 0) * HID + j];
      ha += yv.x * sMh[(cc + 0) * HID + j];
      za += yv.y * sMz[(cc + 1) * HID + j];
      ha += yv.y * sMh[(cc + 1) * HID + j];
      za += yv.z * sMz[(cc + 2) * HID + j];
      ha += yv.z * sMh[(cc + 2) * HID + j];
      za += yv.w * sMz[(cc + 3) * HID + j];
      ha += yv.w * sMh[(cc + 3) * HID + j];
    }
    float z = 1.0f / (1.0f + expf(-za));
    accr += (1.0f - z) * tanhf(ha);
  }
  size_t ai = (size_t)n * HID + j;
  acc[ai] = (tbase == 0 ? 0.f : acc[ai]) + accr;
}

// out[n][o] = (acc[n]/T) . W_out[:,o] + b_out[o]
__global__ __launch_bounds__(256) void out_kernel(const float* __restrict__ acc,
                                                  const float* __restrict__ W_out,
                                                  const float* __restrict__ b_out,
                                                  float* __restrict__ out) {
  __shared__ float sW[HID * OUT_C], sB[OUT_C];
  for (int i = threadIdx.x; i < HID * OUT_C; i += 256) sW[i] = W_out[i];
  if (threadIdx.x < OUT_C) sB[threadIdx.x] = b_out[threadIdx.x];
  __syncthreads();
  unsigned tid = blockIdx.x * 256u + threadIdx.x;
  unsigned n = tid >> 5;
  int o = tid & 31;
  if (n >= NN) return;
  const float* ar = acc + (size_t)n * HID;
  float v = 0.f;
#pragma unroll
  for (int k = 0; k < HID; ++k) v += ar[k] * sW[k * OUT_C + o];
  out[(size_t)n * OUT_C + o] = v * (1.0f / (float)TT) + sB[o];
}

extern "C" void kernel_launch(void* const* d_in, const int* in_sizes, int n_in,
                              void* d_out, int out_size, void* d_ws, size_t ws_size,
                              hipStream_t stream) {
  const float* x     = (const float*)d_in[0];  // [T,N,32]
  const int*   ei    = (const int*)d_in[1];    // [T,2,E]
  const float* ew    = (const float*)d_in[2];  // [T,E]
  const float* Wz    = (const float*)d_in[3];
  const float* bz    = (const float*)d_in[4];
  // d_in[5..6] (Wr,br) dead: H==0 so R unused
  const float* Wh    = (const float*)d_in[7];
  const float* bh    = (const float*)d_in[8];
  const float* Lz_w  = (const float*)d_in[9];
  const float* Lz_b  = (const float*)d_in[10];
  // d_in[11..12] (Lr) dead
  const float* Lh_w  = (const float*)d_in[13];
  const float* Lh_b  = (const float*)d_in[14];
  const float* W_out = (const float*)d_in[15];
  const float* b_out = (const float*)d_in[16];
  float* out = (float*)d_out;

  // sizes (bytes)
  const size_t pcB   = (size_t)NN * 4;
  const size_t csrB  = (size_t)EE * 4;
  const size_t dinvB = (size_t)NN * 4;
  const size_t offB  = (size_t)(NN + 1) * 4;
  const size_t curB  = (size_t)NN * 4;
  const size_t bsumB = (size_t)NBLK * 4;
  const size_t perT  = pcB + csrB + dinvB + offB + curB + bsumB;   // ~4.0 MB
  const size_t xhB   = XPAIRS * 4;                                  // 38.4 MB
  const size_t fixedB = (size_t)(2 * IN_C * HID + 2 * HID) * 4
                      + (size_t)NN * HID * 4 + xhB;                 // ~51.2 MB

  int nt;
  bool csrInOut = false;
  if (ws_size >= fixedB + 12 * perT) {
    nt = 12;
  } else if (ws_size >= fixedB + perT) {
    nt = (int)((ws_size - fixedB) / perT);
    if (nt > 12) nt = 12;
  } else {
    nt = 1;
    csrInOut = true;  // csr (3.2 MB) lives in d_out (6.4 MB), dead until out_kernel
  }

  char* p = (char*)d_ws;
  float* Mz = (float*)p;
  float* Mh = Mz + IN_C * HID;
  float* Bz = Mh + IN_C * HID;
  float* Bh = Bz + HID;
  float* acc = Bh + HID;                      // [N,64]
  __half2* xh = (__half2*)(acc + (size_t)NN * HID);
  p = (char*)xh + xhB;
  unsigned* pc = (unsigned*)p; p += pcB * nt;
  unsigned* csr;
  if (!csrInOut) { csr = (unsigned*)p; p += csrB * nt; }
  else           { csr = (unsigned*)d_out; }
  float* dinv  = (float*)p; p += dinvB * nt;
  int* off     = (int*)p;   p += offB * nt;
  int* cursor  = (int*)p;   p += curB * nt;
  int* bsum    = (int*)p;   p += bsumB * nt;

  prep_kernel<<<dim3(IN_C + 1, 2), 64, 0, stream>>>(Wz, bz, Lz_w, Lz_b, Wh, bh,
                                                    Lh_w, Lh_b, Mz, Bz, Mh, Bh);
  xconv_kernel<<<(unsigned)((XPAIRS + 255) / 256), 256, 0, stream>>>(x, xh);

  for (int tb = 0; tb < TT; tb += nt) {
    int cnt = (TT - tb < nt) ? (TT - tb) : nt;
    hipMemsetAsync(pc, 0, pcB * cnt, stream);
    hist_kernel<<<dim3(EBLK, cnt), 256, 0, stream>>>(ei, ew, pc, tb);
    partial_kernel<<<dim3(NBLK, cnt), SCAN_B, 0, stream>>>(pc, bsum);
    offs_kernel<<<dim3(NBLK, cnt), SCAN_B, 0, stream>>>(bsum, pc, cursor, off, dinv);
    fill_kernel<<<dim3(EBLK, cnt), 256, 0, stream>>>(ei, ew, dinv, cursor, csr, tb);
    gather_dense_kernel<<<NN / GNPB, 256, 0, stream>>>(x, xh, dinv, off, csr,
                                                       Mz, Bz, Mh, Bh, acc, tb, cnt);
  }

  out_kernel<<<(NN * OUT_C + 255) / 256, 256, 0, stream>>>(acc, W_out, b_out, out);
}

// Round 6
// 1172.690 us; speedup vs baseline: 4.3184x; 1.2658x over previous
//
#include <hip/hip_runtime.h>
#include <hip/hip_fp16.h>

#define NN 50000
#define TT 12
#define EE 800000
#define IN_C 32
#define HID 64
#define OUT_C 32
#define EBLK ((EE + 255) / 256)        // 3125
#define GNPB 4                         // nodes per gather block (NN % 4 == 0)
#define W_ELL 64                       // ELL row width (max deg ~45 for Poisson(16))
#define XPAIRS ((size_t)TT * NN * 16)  // half2 elements in x

// ---------------- precompute folded gate matrices ----------------
// Mz = Wz @ Lz_w[:64] (32x64), Bz = bz @ Lz_w[:64] + Lz_b (64); same for h.
__global__ __launch_bounds__(64) void prep_kernel(
    const float* __restrict__ Wz, const float* __restrict__ bz,
    const float* __restrict__ Lzw, const float* __restrict__ Lzb,
    const float* __restrict__ Wh, const float* __restrict__ bh,
    const float* __restrict__ Lhw, const float* __restrict__ Lhb,
    float* __restrict__ Mz, float* __restrict__ Bz,
    float* __restrict__ Mh, float* __restrict__ Bh) {
  const int j = threadIdx.x;
  const int i = blockIdx.x;
  const int h = blockIdx.y;
  const float* W  = h ? Wh  : Wz;
  const float* b  = h ? bh  : bz;
  const float* L  = h ? Lhw : Lzw;
  const float* Lb = h ? Lhb : Lzb;
  float* M = h ? Mh : Mz;
  float* B = h ? Bh : Bz;
  if (i < IN_C) {
    float v = 0.f;
    for (int k = 0; k < HID; ++k) v += W[i * HID + k] * L[k * HID + j];
    M[i * HID + j] = v;
  } else {
    float v = Lb[j];
    for (int k = 0; k < HID; ++k) v += b[k] * L[k * HID + j];
    B[j] = v;
  }
}

// x [T,N,32] fp32 -> fp16 (pairs)
__global__ __launch_bounds__(256) void xconv_kernel(const float* __restrict__ x,
                                                    __half2* __restrict__ xh) {
  size_t i = (size_t)blockIdx.x * 256 + threadIdx.x;
  if (i < XPAIRS) {
    float2 f = ((const float2*)x)[i];
    xh[i] = __floats2half2_rn(f.x, f.y);
  }
}

// per edge: one atomic slot cursor; ell[d][pos] = {u16 src | fp16 w << 16}
__global__ __launch_bounds__(256) void ell_fill_kernel(const int* __restrict__ ei,
                                                       const float* __restrict__ ew,
                                                       int* __restrict__ cntA,
                                                       unsigned* __restrict__ ellA,
                                                       int tbase) {
  int tl = blockIdx.y;
  const int* src = ei + (size_t)(tbase + tl) * 2 * EE;
  const int* dst = src + EE;
  const float* w = ew + (size_t)(tbase + tl) * EE;
  int* cnt = cntA + (size_t)tl * NN;
  unsigned* ell = ellA + (size_t)tl * NN * W_ELL;
  int e = blockIdx.x * 256 + threadIdx.x;
  if (e >= EE) return;
  int s = src[e], d = dst[e];
  unsigned hb = (unsigned)__half_as_ushort(__float2half_rn(w[e]));
  int pos = atomicAdd(&cnt[d], 1);
  if (pos < W_ELL) ell[(size_t)d * W_ELL + pos] = (unsigned)s | (hb << 16);
}

// wave per node: deg = 1 + sum of fp16 weights in ELL row; dinv = rsqrt(deg).
// Also zero-pads row slots [cnt, ceil8(cnt)) so gather is branchless.
__global__ __launch_bounds__(256) void deg_kernel(const int* __restrict__ cntA,
                                                  unsigned* __restrict__ ellA,
                                                  float* __restrict__ dinvA) {
  int tl = blockIdx.y;
  int n = blockIdx.x * GNPB + (threadIdx.x >> 6);
  int lane = threadIdx.x & 63;
  unsigned* row = ellA + ((size_t)tl * NN + n) * W_ELL;
  int cnt = min(cntA[(size_t)tl * NN + n], W_ELL);
  int pad8 = (cnt + 7) & ~7;
  unsigned u = 0;
  if (lane < pad8) u = row[lane];
  if (lane >= cnt && lane < pad8) row[lane] = 0u;  // zero the pad slots
  float wv = (lane < cnt)
                 ? __half2float(__ushort_as_half((unsigned short)(u >> 16)))
                 : 0.f;
#pragma unroll
  for (int m = 1; m < 64; m <<= 1) wv += __shfl_xor(wv, m);
  if (lane == 0) dinvA[(size_t)tl * NN + n] = rsqrtf(1.0f + wv);
}

// mega gather+gate: wave per node, t-loop unrolled x2 (two independent edge
// streams for MLP), 8-way edge split (8 groups x 8 lanes x 4 channels),
// software-pipelined prefetch. Register accumulator across all t.
__global__ __launch_bounds__(256) void gather_dense_kernel(
    const float* __restrict__ x, const __half2* __restrict__ xh,
    const float* __restrict__ dinv_, const int* __restrict__ cnt_,
    const unsigned* __restrict__ ell_,
    const float* __restrict__ Mz, const float* __restrict__ Bz,
    const float* __restrict__ Mh, const float* __restrict__ Bh,
    float* __restrict__ acc, int tbase, int nt) {
  __shared__ float sMz[IN_C * HID], sMh[IN_C * HID], sBz[HID], sBh[HID];
  __shared__ float yt[GNPB][2][IN_C];
  int t = threadIdx.x;
  for (int i = t; i < IN_C * HID; i += 256) {
    sMz[i] = Mz[i];
    sMh[i] = Mh[i];
  }
  if (t < HID) { sBz[t] = Bz[t]; sBh[t] = Bh[t]; }
  __syncthreads();

  int ln = t >> 6;          // wave id == local node
  int lane = t & 63;
  int g = lane >> 3;        // edge group 0..7
  int cc = lane & 7;        // channel quad 0..7 (channels 4cc..4cc+3)
  int n = blockIdx.x * GNPB + ln;
  float accr = 0.f;

  for (int tp = 0; tp < nt; tp += 2) {
    int tA = tp, tB = tp + 1;
    bool hasB = (tB < nt);
    int tBe = hasB ? tB : tA;
    const float* dvTA = dinv_ + (size_t)tA * NN;
    const float* dvTB = dinv_ + (size_t)tBe * NN;
    const unsigned* rowA = ell_ + ((size_t)tA * NN + n) * W_ELL;
    const unsigned* rowB = ell_ + ((size_t)tBe * NN + n) * W_ELL;
    const __half2* xhA = xh + (size_t)(tbase + tA) * NN * 16;
    const __half2* xhB = xh + (size_t)(tbase + tBe) * NN * 16;
    int cA = min(cnt_[(size_t)tA * NN + n], W_ELL);
    int cB = hasB ? min(cnt_[(size_t)tBe * NN + n], W_ELL) : 0;
    int itA = (cA + 7) >> 3, itB = (cB + 7) >> 3;
    int itMax = (itA > itB) ? itA : itB;

    float4 vA = {0.f, 0.f, 0.f, 0.f}, vB = {0.f, 0.f, 0.f, 0.f};
    if (itMax > 0) {
      unsigned uA = (itA > 0) ? rowA[g] : 0u;
      unsigned uB = (itB > 0) ? rowB[g] : 0u;
      float dsA = dvTA[uA & 0xFFFFu];
      float dsB = dvTB[uB & 0xFFFFu];
      uint2 xA = ((const uint2*)(xhA + (size_t)(uA & 0xFFFFu) * 16))[cc];
      uint2 xB = ((const uint2*)(xhB + (size_t)(uB & 0xFFFFu) * 16))[cc];
      for (int i = 0;; ++i) {
        // prefetch next chunk (entry -> dinv[s], x row), both streams
        unsigned uAn = (i + 1 < itA) ? rowA[((i + 1) << 3) + g] : 0u;
        unsigned uBn = (i + 1 < itB) ? rowB[((i + 1) << 3) + g] : 0u;
        float dsAn = dvTA[uAn & 0xFFFFu];
        float dsBn = dvTB[uBn & 0xFFFFu];
        uint2 xAn = ((const uint2*)(xhA + (size_t)(uAn & 0xFFFFu) * 16))[cc];
        uint2 xBn = ((const uint2*)(xhB + (size_t)(uBn & 0xFFFFu) * 16))[cc];
        // consume current chunk (pad entries are 0 -> nm = 0, contributes 0)
        if (i < itA) {
          float nm = __half2float(__ushort_as_half((unsigned short)(uA >> 16))) * dsA;
          float2 p0 = __half22float2(*(const __half2*)&xA.x);
          float2 p1 = __half22float2(*(const __half2*)&xA.y);
          vA.x += nm * p0.x; vA.y += nm * p0.y;
          vA.z += nm * p1.x; vA.w += nm * p1.y;
        }
        if (i < itB) {
          float nm = __half2float(__ushort_as_half((unsigned short)(uB >> 16))) * dsB;
          float2 p0 = __half22float2(*(const __half2*)&xB.x);
          float2 p1 = __half22float2(*(const __half2*)&xB.y);
          vB.x += nm * p0.x; vB.y += nm * p0.y;
          vB.z += nm * p1.x; vB.w += nm * p1.y;
        }
        if (i + 1 >= itMax) break;
        uA = uAn; dsA = dsAn; xA = xAn;
        uB = uBn; dsB = dsBn; xB = xBn;
      }
    }
    // reduce over the 8 edge groups (lane bits 3,4,5)
#pragma unroll
    for (int m = 8; m <= 32; m <<= 1) {
      vA.x += __shfl_xor(vA.x, m); vA.y += __shfl_xor(vA.y, m);
      vA.z += __shfl_xor(vA.z, m); vA.w += __shfl_xor(vA.w, m);
      vB.x += __shfl_xor(vB.x, m); vB.y += __shfl_xor(vB.y, m);
      vB.z += __shfl_xor(vB.z, m); vB.w += __shfl_xor(vB.w, m);
    }
    float dvA = dvTA[n];
    float dvB = dvTB[n];
    if (g == 0) {  // 8 lanes x float4 cover all 32 channels
      const float* xtA = x + (size_t)(tbase + tA) * NN * IN_C;
      float4 xs = ((const float4*)(xtA + (size_t)n * IN_C))[cc];
      float4 o;
      o.x = dvA * (vA.x + dvA * xs.x);
      o.y = dvA * (vA.y + dvA * xs.y);
      o.z = dvA * (vA.z + dvA * xs.z);
      o.w = dvA * (vA.w + dvA * xs.w);
      *(float4*)&yt[ln][0][cc * 4] = o;
      if (hasB) {
        const float* xtB = x + (size_t)(tbase + tB) * NN * IN_C;
        float4 xs2 = ((const float4*)(xtB + (size_t)n * IN_C))[cc];
        float4 o2;
        o2.x = dvB * (vB.x + dvB * xs2.x);
        o2.y = dvB * (vB.y + dvB * xs2.y);
        o2.z = dvB * (vB.z + dvB * xs2.z);
        o2.w = dvB * (vB.w + dvB * xs2.w);
        *(float4*)&yt[ln][1][cc * 4] = o2;
      }
    }
    // gate phase (wave-private LDS: same-wave write->read is in-order)
    int nS = hasB ? 2 : 1;
    for (int s = 0; s < nS; ++s) {
      const float* yrow = yt[ln][s];
      float za = sBz[lane], ha = sBh[lane];
#pragma unroll
      for (int c2 = 0; c2 < IN_C; c2 += 4) {
        float4 yv = *(const float4*)(yrow + c2);
        za += yv.x * sMz[(c2 + 0) * HID + lane];
        ha += yv.x * sMh[(c2 + 0) * HID + lane];
        za += yv.y * sMz[(c2 + 1) * HID + lane];
        ha += yv.y * sMh[(c2 + 1) * HID + lane];
        za += yv.z * sMz[(c2 + 2) * HID + lane];
        ha += yv.z * sMh[(c2 + 2) * HID + lane];
        za += yv.w * sMz[(c2 + 3) * HID + lane];
        ha += yv.w * sMh[(c2 + 3) * HID + lane];
      }
      float z = 1.0f / (1.0f + expf(-za));
      accr += (1.0f - z) * tanhf(ha);
    }
  }
  size_t ai = (size_t)n * HID + lane;
  acc[ai] = (tbase == 0 ? 0.f : acc[ai]) + accr;
}

// out[n][o] = (acc[n]/T) . W_out[:,o] + b_out[o]
__global__ __launch_bounds__(256) void out_kernel(const float* __restrict__ acc,
                                                  const float* __restrict__ W_out,
                                                  const float* __restrict__ b_out,
                                                  float* __restrict__ out) {
  __shared__ float sW[HID * OUT_C], sB[OUT_C];
  for (int i = threadIdx.x; i < HID * OUT_C; i += 256) sW[i] = W_out[i];
  if (threadIdx.x < OUT_C) sB[threadIdx.x] = b_out[threadIdx.x];
  __syncthreads();
  unsigned tid = blockIdx.x * 256u + threadIdx.x;
  unsigned n = tid >> 5;
  int o = tid & 31;
  if (n >= NN) return;
  const float* ar = acc + (size_t)n * HID;
  float v = 0.f;
#pragma unroll
  for (int k = 0; k < HID; ++k) v += ar[k] * sW[k * OUT_C + o];
  out[(size_t)n * OUT_C + o] = v * (1.0f / (float)TT) + sB[o];
}

static inline char* alignp(char* p, size_t a) {
  return (char*)(((size_t)p + a - 1) & ~(a - 1));
}

extern "C" void kernel_launch(void* const* d_in, const int* in_sizes, int n_in,
                              void* d_out, int out_size, void* d_ws, size_t ws_size,
                              hipStream_t stream) {
  const float* x     = (const float*)d_in[0];  // [T,N,32]
  const int*   ei    = (const int*)d_in[1];    // [T,2,E]
  const float* ew    = (const float*)d_in[2];  // [T,E]
  const float* Wz    = (const float*)d_in[3];
  const float* bz    = (const float*)d_in[4];
  // d_in[5..6] (Wr,br) dead: H==0 so R unused
  const float* Wh    = (const float*)d_in[7];
  const float* bh    = (const float*)d_in[8];
  const float* Lz_w  = (const float*)d_in[9];
  const float* Lz_b  = (const float*)d_in[10];
  // d_in[11..12] (Lr) dead
  const float* Lh_w  = (const float*)d_in[13];
  const float* Lh_b  = (const float*)d_in[14];
  const float* W_out = (const float*)d_in[15];
  const float* b_out = (const float*)d_in[16];
  float* out = (float*)d_out;

  // sizes (bytes)
  const size_t ellB  = (size_t)NN * W_ELL * 4;  // 12.8 MB
  const size_t cntB  = (size_t)NN * 4;
  const size_t dinvB = (size_t)NN * 4;
  const size_t perT  = ellB + cntB + dinvB;     // ~13.2 MB
  const size_t xhB   = XPAIRS * 4;              // 38.4 MB
  const size_t fixedB = 4 * ((size_t)2 * IN_C * HID + 2 * HID)  // M/B
                      + (size_t)NN * HID * 4 + xhB + 4096;      // ~51.2 MB

  int nt = 12;
  if (ws_size < fixedB + 12 * perT) {
    nt = (int)((ws_size - fixedB) / perT);
    if (nt < 1) nt = 1;
    if (nt > 12) nt = 12;
  }

  char* p = (char*)d_ws;
  float* Mz = (float*)p;
  float* Mh = Mz + IN_C * HID;
  float* Bz = Mh + IN_C * HID;
  float* Bh = Bz + HID;
  float* acc = Bh + HID;  // [N,64]
  p = alignp((char*)(acc + (size_t)NN * HID), 256);
  __half2* xh = (__half2*)p;
  p = alignp(p + xhB, 256);
  unsigned* ell = (unsigned*)p; p += ellB * nt;
  int* cnt = (int*)p;           p += cntB * nt;
  float* dinv = (float*)p;      p += dinvB * nt;

  prep_kernel<<<dim3(IN_C + 1, 2), 64, 0, stream>>>(Wz, bz, Lz_w, Lz_b, Wh, bh,
                                                    Lh_w, Lh_b, Mz, Bz, Mh, Bh);
  xconv_kernel<<<(unsigned)((XPAIRS + 255) / 256), 256, 0, stream>>>(x, xh);

  for (int tb = 0; tb < TT; tb += nt) {
    int c = (TT - tb < nt) ? (TT - tb) : nt;
    hipMemsetAsync(cnt, 0, cntB * c, stream);
    ell_fill_kernel<<<dim3(EBLK, c), 256, 0, stream>>>(ei, ew, cnt, ell, tb);
    deg_kernel<<<dim3(NN / GNPB, c), 256, 0, stream>>>(cnt, ell, dinv);
    gather_dense_kernel<<<NN / GNPB, 256, 0, stream>>>(x, xh, dinv, cnt, ell,
                                                       Mz, Bz, Mh, Bh, acc, tb, c);
  }

  out_kernel<<<(NN * OUT_C + 255) / 256, 256, 0, stream>>>(acc, W_out, b_out, out);
}